// Round 2
// baseline (146.437 us; speedup 1.0000x reference)
//
#include <hip/hip_runtime.h>

// Problem constants (from reference): B=8, E=512, L=4096, D=256, all fp32.
#define B_N 8
#define E_N 512
#define L_N 4096
#define D_N 256

#define SPLITK 8
#define KC_LEN (L_N / SPLITK)   // 512
#define BK 64
#define KC_ITERS (KC_LEN / BK)  // 8

#define ET 128                  // E tile
#define DT 128                  // D tile
#define NTHREADS 512

typedef __attribute__((ext_vector_type(8))) short short8;   // 8 bf16 (MFMA A/B frag)
typedef __attribute__((ext_vector_type(4))) short short4v;  // 4 bf16 = 8B LDS store
typedef __attribute__((ext_vector_type(4))) float f32x4;    // MFMA acc / global float4

// round-to-nearest-even fp32 -> bf16 bits (proven correct vs 0.5 tolerance; do not
// swap for __float2bfloat16 whose rounding mode is header-version-dependent)
__device__ __forceinline__ unsigned short f2bf(float f) {
    unsigned u = __float_as_uint(f);
    u += 0x7fffu + ((u >> 16) & 1u);
    return (unsigned short)(u >> 16);
}

// LDS tile: [row][64 k] bf16, 128 B per row, NO pad. Bank-conflict fix is the
// m214-verified 16B-chunk XOR swizzle: chunk' = chunk ^ (row & 7).
// k must be a multiple of 4 (8B stores) or 8 (16B frag reads) at call sites.
__device__ __forceinline__ int swz(int row, int k) {
    return row * 64 + ((((k >> 3) ^ (row & 7)) << 3) | (k & 7));
}

__global__ __launch_bounds__(NTHREADS, 4)   // cap VGPR at 128 -> 2 blocks/CU
void mp_gemm(const float* __restrict__ doc,   // [B, L, D]
             const float* __restrict__ map,   // [B, E, L]
             const float* __restrict__ lens,  // [B, E]
             float* __restrict__ out)         // [B, E, D] (pre-zeroed; atomic accumulate)
{
    // double-buffered swizzled tiles: 4 x 16 KiB = 64 KiB -> 2 blocks/CU fit in 160 KiB
    __shared__ unsigned short As[2][ET * 64];   // As[m][k] : map tile, K-contig
    __shared__ unsigned short Bs[2][DT * 64];   // Bs[n][k] : doc tile transposed
    __shared__ float invLen[ET];

    // XCD-chunked swizzle (unchanged from R1): each XCD owns 8 complete (b,kc)
    // groups; the 8 tiles of a group share doc/map panels in that XCD's L2.
    const int p    = (int)blockIdx.x;            // 0..511
    const int w    = ((p & 7) << 6) | (p >> 3);
    const int tile = w & 7;        // et*2 + dt
    const int grp  = w >> 3;       // 0..63
    const int b    = grp & 7;
    const int kc   = grp >> 3;     // 0..7

    const int e0  = (tile >> 1) * ET;   // 4 E tiles
    const int d0  = (tile & 1) * DT;    // 2 D tiles
    const int kc0 = kc * KC_LEN;

    const float* docB = doc + (size_t)b * L_N * D_N;
    const float* mapB = map + (size_t)b * E_N * L_N;
    float*       outB = out + (size_t)b * E_N * D_N;

    const int tid  = threadIdx.x;
    const int lane = tid & 63;
    const int wave = tid >> 6;     // 0..7

    if (tid < ET) invLen[tid] = 1.0f / lens[(size_t)b * E_N + e0 + tid];

    // ---- staging assignments ----
    // A tile 128(m) x 64(k) fp32: thread t -> rows (t>>4)+32r, col4 = t&15
    //   per instruction: 16 lanes x 16B = 256B contiguous per row
    const int aRow0 = tid >> 4;    // 0..31
    const int aCol4 = tid & 15;
    // B tile 64(k) x 128(n) fp32: one 4(k)x4(n) micro-block per thread.
    // kb = tid&15 so the 16B LDS chunk index VARIES across lanes (conflict fix);
    // global reads become 16 k-rows x 64B segments per instruction (acceptable).
    const int kb = tid & 15;       // k block (0..15)
    const int nb = tid >> 4;       // n block (0..31)

    f32x4 ar[4], br[4];

    #define LOAD_SET(K0)                                                                   \
        do {                                                                               \
            _Pragma("unroll")                                                              \
            for (int r = 0; r < 4; ++r)                                                    \
                ar[r] = *(const f32x4*)(mapB + (size_t)(e0 + aRow0 + r * 32) * L_N +       \
                                        (K0) + aCol4 * 4);                                 \
            _Pragma("unroll")                                                              \
            for (int i = 0; i < 4; ++i)                                                    \
                br[i] = *(const f32x4*)(docB + (size_t)((K0) + kb * 4 + i) * D_N +         \
                                        d0 + nb * 4);                                      \
        } while (0)

    // ---- compute setup: 8 waves in 2(m) x 4(n) grid; each wave 64x32 output ----
    const int wm = wave >> 2;      // 0..1 : 64-row block
    const int wn = wave & 3;       // 0..3 : 32-col block
    const int fm = lane & 15;
    const int q  = lane >> 4;

    f32x4 acc[4][2] = {};

    LOAD_SET(kc0);                 // prologue: issue tile-0 loads

    #pragma unroll 2
    for (int it = 0; it < KC_ITERS; ++it) {
        const int bi = it & 1;

        // regs -> LDS buf[bi] (fp32->bf16 convert; B transposed 4x4).
        // Compiler inserts counted vmcnt waits for ar/br here.
        #pragma unroll
        for (int r = 0; r < 4; ++r) {
            short4v wv;
            wv[0] = (short)f2bf(ar[r][0]);
            wv[1] = (short)f2bf(ar[r][1]);
            wv[2] = (short)f2bf(ar[r][2]);
            wv[3] = (short)f2bf(ar[r][3]);
            *(short4v*)&As[bi][swz(aRow0 + r * 32, aCol4 * 4)] = wv;
        }
        #pragma unroll
        for (int j = 0; j < 4; ++j) {
            short4v wv;
            wv[0] = (short)f2bf(br[0][j]);
            wv[1] = (short)f2bf(br[1][j]);
            wv[2] = (short)f2bf(br[2][j]);
            wv[3] = (short)f2bf(br[3][j]);
            *(short4v*)&Bs[bi][swz(nb * 4 + j, kb * 4)] = wv;
        }

        // issue next-tile loads NOW; sched_barrier pins them above the barrier
        // so they stay in flight across the whole MFMA phase (do NOT let the
        // compiler sink them -- that was R1's hidden serialization, VGPR=52).
        if (it + 1 < KC_ITERS) LOAD_SET(kc0 + (it + 1) * BK);
        __builtin_amdgcn_sched_barrier(0);

        // Raw barrier: wait only on LDS ops (writes visible), NOT vmcnt --
        // __syncthreads() would drain the in-flight global loads.
        asm volatile("s_waitcnt lgkmcnt(0)" ::: "memory");
        __builtin_amdgcn_s_barrier();
        __builtin_amdgcn_sched_barrier(0);

        // compute on staged 128x128x64 tile: 2 K-steps of 32.
        // Single barrier per iter is safe: writes(it+1) target buf[bi^1],
        // and reads(it) complete before any wave can pass barrier(it+1).
        #pragma unroll
        for (int kk = 0; kk < 2; ++kk) {
            short8 af[4], bf[2];
            #pragma unroll
            for (int mi = 0; mi < 4; ++mi) {
                const int m = wm * 64 + mi * 16 + fm;
                af[mi] = *(const short8*)&As[bi][swz(m, kk * 32 + q * 8)];
            }
            #pragma unroll
            for (int ni = 0; ni < 2; ++ni) {
                const int n = wn * 32 + ni * 16 + fm;
                bf[ni] = *(const short8*)&Bs[bi][swz(n, kk * 32 + q * 8)];
            }
            #pragma unroll
            for (int mi = 0; mi < 4; ++mi)
                #pragma unroll
                for (int ni = 0; ni < 2; ++ni)
                    acc[mi][ni] = __builtin_amdgcn_mfma_f32_16x16x32_bf16(
                        af[mi], bf[ni], acc[mi][ni], 0, 0, 0);
        }
    }

    // ---- epilogue: scale partial by invLen (linear in split-K) and atomically accumulate.
    // C/D layout: col = lane&15, row = (lane>>4)*4 + i
    #pragma unroll
    for (int mi = 0; mi < 4; ++mi) {
        const int rLoc = wm * 64 + mi * 16 + q * 4;
        #pragma unroll
        for (int ni = 0; ni < 2; ++ni) {
            const int c = d0 + wn * 32 + ni * 16 + fm;
            #pragma unroll
            for (int i = 0; i < 4; ++i) {
                const int rr = rLoc + i;
                atomicAdd(&outB[(size_t)(e0 + rr) * D_N + c], acc[mi][ni][i] * invLen[rr]);
            }
        }
    }
}

extern "C" void kernel_launch(void* const* d_in, const int* in_sizes, int n_in,
                              void* d_out, int out_size, void* d_ws, size_t ws_size,
                              hipStream_t stream) {
    const float* doc  = (const float*)d_in[0];  // doc_state [B,L,D]
    const float* map  = (const float*)d_in[1];  // entity_mapping [B,E,L]
    const float* lens = (const float*)d_in[2];  // entity_lens [B,E]
    float* out = (float*)d_out;                 // [B,E,D] fp32

    // d_out is poisoned 0xAA before every call; split-K accumulates atomically.
    hipMemsetAsync(out, 0, (size_t)out_size * sizeof(float), stream);

    dim3 grid(SPLITK * 8 * B_N);   // 512 blocks: (E/128)*(D/128)=8 tiles x 8 b x 8 kc
    mp_gemm<<<grid, NTHREADS, 0, stream>>>(doc, map, lens, out);
}

// Round 3
// 141.792 us; speedup vs baseline: 1.0328x; 1.0328x over previous
//
#include <hip/hip_runtime.h>

// Problem constants (from reference): B=8, E=512, L=4096, D=256, all fp32.
#define B_N 8
#define E_N 512
#define L_N 4096
#define D_N 256

#define SPLITK 8
#define KC_LEN (L_N / SPLITK)   // 512
#define BK 64
#define KC_ITERS (KC_LEN / BK)  // 8

#define ET 128                  // E tile
#define DT 128                  // D tile
#define NTHREADS 512

#define SLICE_ELEMS (B_N * E_N * D_N)           // 1M floats = 4 MB per split slice
#define WS_FLOATS   (SPLITK * SLICE_ELEMS)      // 32 MB workspace

typedef __attribute__((ext_vector_type(8))) short short8;   // 8 bf16 (MFMA A/B frag)
typedef __attribute__((ext_vector_type(4))) short short4v;  // 4 bf16 = 8B LDS store
typedef __attribute__((ext_vector_type(4))) float f32x4;    // MFMA acc / global float4

// round-to-nearest-even fp32 -> bf16 bits (proven correct vs 0.5 tolerance; do not
// swap for __float2bfloat16 whose rounding mode is header-version-dependent)
__device__ __forceinline__ unsigned short f2bf(float f) {
    unsigned u = __float_as_uint(f);
    u += 0x7fffu + ((u >> 16) & 1u);
    return (unsigned short)(u >> 16);
}

// LDS tile: [row][64 k] bf16, 128 B per row, NO pad. 16B-chunk XOR swizzle
// (verified R2: SQ_LDS_BANK_CONFLICT 5.2M -> 0). k multiple of 4 at call sites.
__device__ __forceinline__ int swz(int row, int k) {
    return row * 64 + ((((k >> 3) ^ (row & 7)) << 3) | (k & 7));
}

// ---------------- Stage 1: split-K partial GEMM, NO atomics ----------------
__global__ __launch_bounds__(NTHREADS, 4)
void mp_gemm(const float* __restrict__ doc,   // [B, L, D]
             const float* __restrict__ map,   // [B, E, L]
             float* __restrict__ ws)          // [SPLITK, B, E, D] partials
{
    // double-buffered swizzled tiles: 4 x 16 KiB = 64 KiB -> 2 blocks/CU
    __shared__ unsigned short As[2][ET * 64];   // As[m][k] : map tile, K-contig
    __shared__ unsigned short Bs[2][DT * 64];   // Bs[n][k] : doc tile transposed

    // XCD-chunked swizzle: XCD(p)=p%8 (assumed RR); each XCD owns 8 complete
    // (b,kc) groups whose 8 tiles share doc/map panels in that XCD's L2.
    // Note XCD == kc under this mapping: fine now that kc-partials go to
    // PRIVATE workspace slices (R2's cross-XCD same-line atomics are gone).
    const int p    = (int)blockIdx.x;            // 0..511
    const int w    = ((p & 7) << 6) | (p >> 3);
    const int tile = w & 7;        // et*2 + dt
    const int grp  = w >> 3;       // 0..63
    const int b    = grp & 7;
    const int kc   = grp >> 3;     // 0..7

    const int e0  = (tile >> 1) * ET;   // 4 E tiles
    const int d0  = (tile & 1) * DT;    // 2 D tiles
    const int kc0 = kc * KC_LEN;

    const float* docB = doc + (size_t)b * L_N * D_N;
    const float* mapB = map + (size_t)b * E_N * L_N;
    float* wsB = ws + (size_t)kc * SLICE_ELEMS + (size_t)b * E_N * D_N;

    const int tid  = threadIdx.x;
    const int lane = tid & 63;
    const int wave = tid >> 6;     // 0..7

    // ---- staging assignments ----
    // A tile 128(m) x 64(k) fp32: thread t -> rows (t>>4)+32r, col4 = t&15
    const int aRow0 = tid >> 4;    // 0..31
    const int aCol4 = tid & 15;
    // B tile 64(k) x 128(n) fp32: one 4(k)x4(n) micro-block per thread;
    // kb = tid&15 so the LDS 16B chunk index varies across lanes.
    const int kb = tid & 15;       // k block (0..15)
    const int nb = tid >> 4;       // n block (0..31)

    f32x4 ar[4], br[4];

    #define LOAD_SET(K0)                                                                   \
        do {                                                                               \
            _Pragma("unroll")                                                              \
            for (int r = 0; r < 4; ++r)                                                    \
                ar[r] = *(const f32x4*)(mapB + (size_t)(e0 + aRow0 + r * 32) * L_N +       \
                                        (K0) + aCol4 * 4);                                 \
            _Pragma("unroll")                                                              \
            for (int i = 0; i < 4; ++i)                                                    \
                br[i] = *(const f32x4*)(docB + (size_t)((K0) + kb * 4 + i) * D_N +         \
                                        d0 + nb * 4);                                      \
        } while (0)

    // ---- compute setup: 8 waves in 2(m) x 4(n) grid; each wave 64x32 output ----
    const int wm = wave >> 2;      // 0..1 : 64-row block
    const int wn = wave & 3;       // 0..3 : 32-col block
    const int fm = lane & 15;
    const int q  = lane >> 4;

    f32x4 acc[4][2] = {};

    LOAD_SET(kc0);                 // prologue: issue tile-0 loads

    #pragma unroll 2
    for (int it = 0; it < KC_ITERS; ++it) {
        const int bi = it & 1;

        // regs -> LDS buf[bi] (fp32->bf16 convert; B transposed 4x4).
        #pragma unroll
        for (int r = 0; r < 4; ++r) {
            short4v wv;
            wv[0] = (short)f2bf(ar[r][0]);
            wv[1] = (short)f2bf(ar[r][1]);
            wv[2] = (short)f2bf(ar[r][2]);
            wv[3] = (short)f2bf(ar[r][3]);
            *(short4v*)&As[bi][swz(aRow0 + r * 32, aCol4 * 4)] = wv;
        }
        #pragma unroll
        for (int j = 0; j < 4; ++j) {
            short4v wv;
            wv[0] = (short)f2bf(br[0][j]);
            wv[1] = (short)f2bf(br[1][j]);
            wv[2] = (short)f2bf(br[2][j]);
            wv[3] = (short)f2bf(br[3][j]);
            *(short4v*)&Bs[bi][swz(nb * 4 + j, kb * 4)] = wv;
        }

        // Issue next-tile loads unconditionally (wrap to tile 0 on last iter:
        // valid addresses, results unused) -- keeps the loads in the main
        // scheduling region, no branch for the compiler to sink them behind.
        LOAD_SET(kc0 + (((it + 1) & (KC_ITERS - 1)) * BK));
        __builtin_amdgcn_sched_barrier(0);

        // Raw barrier: wait only on LDS ops, NOT vmcnt -- keep globals in flight.
        asm volatile("s_waitcnt lgkmcnt(0)" ::: "memory");
        __builtin_amdgcn_s_barrier();
        __builtin_amdgcn_sched_barrier(0);

        // compute on staged 128x128x64 tile: 2 K-steps of 32.
        #pragma unroll
        for (int kk = 0; kk < 2; ++kk) {
            short8 af[4], bf[2];
            #pragma unroll
            for (int mi = 0; mi < 4; ++mi) {
                const int m = wm * 64 + mi * 16 + fm;
                af[mi] = *(const short8*)&As[bi][swz(m, kk * 32 + q * 8)];
            }
            #pragma unroll
            for (int ni = 0; ni < 2; ++ni) {
                const int n = wn * 32 + ni * 16 + fm;
                bf[ni] = *(const short8*)&Bs[bi][swz(n, kk * 32 + q * 8)];
            }
            #pragma unroll
            for (int mi = 0; mi < 4; ++mi)
                #pragma unroll
                for (int ni = 0; ni < 2; ++ni)
                    acc[mi][ni] = __builtin_amdgcn_mfma_f32_16x16x32_bf16(
                        af[mi], bf[ni], acc[mi][ni], 0, 0, 0);
        }
    }

    // ---- epilogue: plain stores of the partial tile to this block's private
    // workspace slice. C/D layout: col = lane&15, row = (lane>>4)*4 + i.
    // Per store instruction the wave writes 4 rows x 64B segments -- acceptable.
    #pragma unroll
    for (int mi = 0; mi < 4; ++mi) {
        const int rLoc = wm * 64 + mi * 16 + q * 4;
        #pragma unroll
        for (int ni = 0; ni < 2; ++ni) {
            const int c = d0 + wn * 32 + ni * 16 + fm;
            #pragma unroll
            for (int i = 0; i < 4; ++i) {
                const int rr = rLoc + i;
                wsB[(size_t)(e0 + rr) * D_N + c] = acc[mi][ni][i];
            }
        }
    }
}

// ---------------- Stage 2: reduce slices + scale by 1/len ----------------
__global__ __launch_bounds__(256)
void mp_reduce(const float* __restrict__ ws,    // [SPLITK, B*E*D]
               const float* __restrict__ lens,  // [B, E]
               float* __restrict__ out)         // [B*E*D]
{
    const int t = (int)blockIdx.x * 256 + (int)threadIdx.x;  // float4 index
    const size_t off = (size_t)t * 4;
    const int be = t >> 6;            // D/4 = 64 float4 per (b,e) row

    f32x4 s = {};
    #pragma unroll
    for (int k = 0; k < SPLITK; ++k) {
        const f32x4 v = *(const f32x4*)(ws + (size_t)k * SLICE_ELEMS + off);
        s += v;
    }
    const float il = 1.0f / lens[be];
    s *= il;
    *(f32x4*)(out + off) = s;
}

extern "C" void kernel_launch(void* const* d_in, const int* in_sizes, int n_in,
                              void* d_out, int out_size, void* d_ws, size_t ws_size,
                              hipStream_t stream) {
    const float* doc  = (const float*)d_in[0];  // doc_state [B,L,D]
    const float* map  = (const float*)d_in[1];  // entity_mapping [B,E,L]
    const float* lens = (const float*)d_in[2];  // entity_lens [B,E]
    float* out = (float*)d_out;                 // [B,E,D] fp32
    float* ws  = (float*)d_ws;                  // needs 32 MB (SPLITK slices)

    // No memset needed: stage 1 fully writes every ws slice element it owns,
    // stage 2 fully overwrites out.
    dim3 grid1(SPLITK * 8 * B_N);   // 512 blocks: 8 tiles x 8 b x 8 kc
    mp_gemm<<<grid1, NTHREADS, 0, stream>>>(doc, map, ws);

    dim3 grid2(SLICE_ELEMS / 4 / 256);  // 1024 blocks
    mp_reduce<<<grid2, 256, 0, stream>>>(ws, lens, out);
}